// Round 1
// 187.597 us; speedup vs baseline: 1.0435x; 1.0435x over previous
//
#include <hip/hip_runtime.h>
#include <math.h>

// Problem constants (fixed by setup_inputs): B=32, S=64, H=256.
#define EPSF 1e-8f
constexpr int B = 32;
constexpr int S = 64;
constexpr int H = 256;                 // floats per cell
constexpr int H4 = H / 4;              // float4 per cell = 64 (one per lane)
constexpr int CELLS_PER_BATCH = S * S; // 4096
constexpr int CELLS = B * CELLS_PER_BATCH; // 131072
constexpr int CELLS_PER_WAVE = 16;     // mask-gated: ~35% of these actually loaded
constexpr int WAVES_PER_BLOCK = 4;     // 256 threads
constexpr int CELLS_PER_BLOCK = CELLS_PER_WAVE * WAVES_PER_BLOCK; // 64

// ws layout (floats):
//   [0..31]                : inv_qnorm[b] = 1/(||pos_query[b]|| + eps)
//   [64 + b*32]            : epos[b]   (cacheline-spread: 128 B stride)
//   [64 + b*32 + 16]       : eneg[b]   (separate 64 B line from epos[b])
#define WS_ACC_BASE 64
#define WS_ACC_STRIDE 32
#define WS_NEG_OFF 16

// ---------------- kernel 1: q-norms + zero accumulators ----------------
__global__ __launch_bounds__(64) void prep_kernel(const float* __restrict__ pq,
                                                  float* __restrict__ ws) {
    int b = blockIdx.x;          // 0..31
    int lane = threadIdx.x;      // 0..63
    float4 v = ((const float4*)pq)[b * H4 + lane];
    float ss = v.x * v.x + v.y * v.y + v.z * v.z + v.w * v.w;
    #pragma unroll
    for (int off = 32; off > 0; off >>= 1) ss += __shfl_xor(ss, off);
    if (lane == 0) {
        ws[b] = 1.0f / (sqrtf(ss) + EPSF);
        ws[WS_ACC_BASE + b * WS_ACC_STRIDE] = 0.0f;
        ws[WS_ACC_BASE + b * WS_ACC_STRIDE + WS_NEG_OFF] = 0.0f;
    }
}

// ---------------- kernel 2: main pass, mask-gated over (b,i,j) cells ----------------
// Only ~35% of cells are in mask_pos|mask_neg; the rest contribute nothing to the
// loss, so we skip their 1 KiB tmap row entirely. Per wave: ballot the 16 mask
// words into a wave-uniform bitmask, then walk set bits with a 1-deep float4
// prefetch so the next active cell's load is in flight during the reduce chain.
__global__ __launch_bounds__(256) void main_kernel(const float* __restrict__ tmap,
                                                   const float* __restrict__ pq,
                                                   const int* __restrict__ mask_pos,
                                                   const int* __restrict__ mask_neg,
                                                   float* __restrict__ ws) {
    int tid = threadIdx.x;
    int lane = tid & 63;
    int wid = tid >> 6;
    int cellBase = blockIdx.x * CELLS_PER_BLOCK + wid * CELLS_PER_WAVE;
    int b = cellBase >> 12;  // / CELLS_PER_BATCH; block never straddles a batch (4096%64==0)

    // wave-invariant: this batch's query fragment + normalization scale
    float4 q4 = ((const float4*)pq)[b * H4 + lane];
    float scale = ws[b] * (1.0f / (1.0f + EPSF));  // second-normalize eps factor

    // lanes 0..15 fetch this wave's mask words (64 B coalesced), ballot to bitmask
    int mp = 0, mn = 0;
    if (lane < CELLS_PER_WAVE) {
        mp = mask_pos[cellBase + lane];
        mn = mask_neg[cellBase + lane];
    }
    unsigned long long bp = __ballot(mp != 0);
    unsigned long long bn = __ballot(mn != 0);
    unsigned long long act = bp | bn;   // wave-uniform; bits 0..15 only

    float wp = 0.0f, wn = 0.0f;

    if (act) {
        const float4* t4 = (const float4*)tmap;
        int k = __ffsll(act) - 1;
        unsigned long long rem = act & (act - 1);
        float4 t = t4[(cellBase + k) * H4 + lane];
        for (;;) {
            // prefetch next active cell while we reduce the current one
            int kn = -1;
            float4 tnext;
            if (rem) {
                kn = __ffsll(rem) - 1;
                rem &= rem - 1;
                tnext = t4[(cellBase + kn) * H4 + lane];
            }
            float d  = t.x * q4.x + t.y * q4.y + t.z * q4.z + t.w * q4.w;
            float ss = t.x * t.x + t.y * t.y + t.z * t.z + t.w * t.w;
            #pragma unroll
            for (int off = 32; off > 0; off >>= 1) {
                d  += __shfl_xor(d, off);
                ss += __shfl_xor(ss, off);
            }
            // s = dot(t,q)/(||t||*(1+eps)) * inv_qnorm  (all lanes hold same value)
            float s = d * scale * rsqrtf(ss);
            float e = __expf(s);  // TAO = 1
            if ((bp >> k) & 1) wp += e;
            if ((bn >> k) & 1) wn += e;
            if (kn < 0) break;
            k = kn; t = tnext;
        }
    }

    __shared__ float sp[WAVES_PER_BLOCK], sn[WAVES_PER_BLOCK];
    if (lane == 0) { sp[wid] = wp; sn[wid] = wn; }
    __syncthreads();
    if (tid == 0) {
        float tp = 0.0f, tn = 0.0f;
        #pragma unroll
        for (int w = 0; w < WAVES_PER_BLOCK; ++w) { tp += sp[w]; tn += sn[w]; }
        atomicAdd(&ws[WS_ACC_BASE + b * WS_ACC_STRIDE], tp);
        atomicAdd(&ws[WS_ACC_BASE + b * WS_ACC_STRIDE + WS_NEG_OFF], tn);
    }
}

// ---------------- kernel 3: per-batch loss + average ----------------
__global__ __launch_bounds__(64) void final_kernel(const float* __restrict__ ws,
                                                   float* __restrict__ out) {
    int lane = threadIdx.x;  // 0..63
    float li = 0.0f;
    int v = 0;
    if (lane < B) {
        float ep = ws[WS_ACC_BASE + lane * WS_ACC_STRIDE];
        float en = ws[WS_ACC_BASE + lane * WS_ACC_STRIDE + WS_NEG_OFF];
        if (ep > 0.0f && en > 0.0f) {  // == any(mask_pos) && any(mask_neg), since exp>0
            v = 1;
            li = -logf(ep / (ep + en + EPSF));
        }
    }
    #pragma unroll
    for (int off = 32; off > 0; off >>= 1) {
        li += __shfl_xor(li, off);
        v  += __shfl_xor(v, off);
    }
    if (lane == 0) out[0] = li / (float)(v > 0 ? v : 1);
}

extern "C" void kernel_launch(void* const* d_in, const int* in_sizes, int n_in,
                              void* d_out, int out_size, void* d_ws, size_t ws_size,
                              hipStream_t stream) {
    const float* pos_query = (const float*)d_in[0];  // (B,H) fp32
    const float* tmap      = (const float*)d_in[1];  // (B,S,S,H) fp32
    const int*   mask_pos  = (const int*)d_in[2];    // (B,S,S) bool -> int32
    const int*   mask_neg  = (const int*)d_in[3];
    float* out = (float*)d_out;
    float* ws  = (float*)d_ws;

    prep_kernel<<<B, 64, 0, stream>>>(pos_query, ws);
    main_kernel<<<CELLS / CELLS_PER_BLOCK, 256, 0, stream>>>(tmap, pos_query,
                                                             mask_pos, mask_neg, ws);
    final_kernel<<<1, 64, 0, stream>>>(ws, out);
}

// Round 2
// 184.731 us; speedup vs baseline: 1.0597x; 1.0155x over previous
//
#include <hip/hip_runtime.h>
#include <math.h>

// Problem constants (fixed by setup_inputs): B=32, S=64, H=256.
#define EPSF 1e-8f
constexpr int B = 32;
constexpr int S = 64;
constexpr int H = 256;                 // floats per cell
constexpr int H4 = H / 4;              // float4 per cell = 64
constexpr int CELLS_PER_BATCH = S * S; // 4096
constexpr int CELLS = B * CELLS_PER_BATCH; // 131072
constexpr int CELLS_PER_WAVE = 32;     // mask window per wave (~11.2 active avg)
constexpr int WAVES_PER_BLOCK = 4;     // 256 threads
constexpr int CELLS_PER_BLOCK = CELLS_PER_WAVE * WAVES_PER_BLOCK; // 128
constexpr int BLOCKS_PER_BATCH = CELLS_PER_BATCH / CELLS_PER_BLOCK; // 32
constexpr int GRID = CELLS / CELLS_PER_BLOCK; // 1024

// ws layout: float2 partial[sub * B + b], sub in [0,32), b in [0,32)  (8 KB)
// Written non-atomically by each block (no zeroing needed, no prep kernel).

// ---------------- kernel 1: main pass, mask-gated, 16-lane groups ----------------
// Each wave owns 32 consecutive cells of one batch. Ballot the masks into a
// wave-uniform bitmask; each loop iteration assigns up to 4 active cells to the
// wave's four 16-lane groups. Lane p of a group loads 4 float4s of its cell
// (p, p+16, p+32, p+48) -> per load instruction the wave touches 4 contiguous
// 256 B segments (fully coalesced). Within-cell reduce is 4 butterfly levels
// shared by 4 cells = 2 shuffles/cell (vs 12 for whole-wave cells).
__global__ __launch_bounds__(256) void main_kernel(const float* __restrict__ tmap,
                                                   const float* __restrict__ pq,
                                                   const int* __restrict__ mask_pos,
                                                   const int* __restrict__ mask_neg,
                                                   float* __restrict__ ws) {
    int tid = threadIdx.x;
    int lane = tid & 63;
    int wid = tid >> 6;
    int b   = blockIdx.x >> 5;   // / BLOCKS_PER_BATCH; block never straddles a batch
    int sub = blockIdx.x & 31;
    int waveBase = blockIdx.x * CELLS_PER_BLOCK + wid * CELLS_PER_WAVE;

    int p = lane & 15;   // position within 16-lane group
    int g = lane >> 4;   // group 0..3

    // q fragment: lane p holds q[4*(p+16m)..] for m=0..3 (same in all 4 groups)
    const float4* q4 = (const float4*)pq + (size_t)b * H4;
    float4 qm0 = q4[p], qm1 = q4[p + 16], qm2 = q4[p + 32], qm3 = q4[p + 48];

    // wave-local q-norm (replaces prep kernel): ||q||^2 via within-group reduce
    float ssq = qm0.x*qm0.x + qm0.y*qm0.y + qm0.z*qm0.z + qm0.w*qm0.w
              + qm1.x*qm1.x + qm1.y*qm1.y + qm1.z*qm1.z + qm1.w*qm1.w
              + qm2.x*qm2.x + qm2.y*qm2.y + qm2.z*qm2.z + qm2.w*qm2.w
              + qm3.x*qm3.x + qm3.y*qm3.y + qm3.z*qm3.z + qm3.w*qm3.w;
    #pragma unroll
    for (int off = 1; off <= 8; off <<= 1) ssq += __shfl_xor(ssq, off);
    float scale = (1.0f / (sqrtf(ssq) + EPSF)) * (1.0f / (1.0f + EPSF));

    // lanes 0..31 fetch this wave's mask words (128 B coalesced), ballot
    int mp = 0, mn = 0;
    if (lane < CELLS_PER_WAVE) {
        mp = mask_pos[waveBase + lane];
        mn = mask_neg[waveBase + lane];
    }
    unsigned bp = (unsigned)__ballot(mp != 0);
    unsigned bn = (unsigned)__ballot(mn != 0);
    unsigned rem = bp | bn;   // wave-uniform; bits 0..31

    const float4* t4 = (const float4*)tmap;
    float wp = 0.0f, wn = 0.0f;

    while (rem) {
        // extract up to 4 set bits (wave-uniform -> SALU)
        int k0 = __ffs(rem) - 1; rem &= rem - 1;
        int k1 = -1, k2 = -1, k3 = -1;
        if (rem) { k1 = __ffs(rem) - 1; rem &= rem - 1;
            if (rem) { k2 = __ffs(rem) - 1; rem &= rem - 1;
                if (rem) { k3 = __ffs(rem) - 1; rem &= rem - 1; } } }
        int kg = (g == 0) ? k0 : (g == 1) ? k1 : (g == 2) ? k2 : k3;
        if (kg >= 0) {  // uniform within each 16-lane group
            const float4* cp = t4 + (size_t)(waveBase + kg) * H4 + p;
            float4 t0 = cp[0], t1 = cp[16], t2 = cp[32], t3 = cp[48];
            float d  = t0.x*qm0.x + t0.y*qm0.y + t0.z*qm0.z + t0.w*qm0.w
                     + t1.x*qm1.x + t1.y*qm1.y + t1.z*qm1.z + t1.w*qm1.w
                     + t2.x*qm2.x + t2.y*qm2.y + t2.z*qm2.z + t2.w*qm2.w
                     + t3.x*qm3.x + t3.y*qm3.y + t3.z*qm3.z + t3.w*qm3.w;
            float ss = t0.x*t0.x + t0.y*t0.y + t0.z*t0.z + t0.w*t0.w
                     + t1.x*t1.x + t1.y*t1.y + t1.z*t1.z + t1.w*t1.w
                     + t2.x*t2.x + t2.y*t2.y + t2.z*t2.z + t2.w*t2.w
                     + t3.x*t3.x + t3.y*t3.y + t3.z*t3.z + t3.w*t3.w;
            // reduce within the 16-lane group (all referenced lanes active)
            #pragma unroll
            for (int off = 1; off <= 8; off <<= 1) {
                d  += __shfl_xor(d, off);
                ss += __shfl_xor(ss, off);
            }
            float s = d * scale * rsqrtf(ss);
            float e = __expf(s);  // TAO = 1
            if ((bp >> kg) & 1) wp += e;
            if ((bn >> kg) & 1) wn += e;
        }
    }

    // combine the 4 groups (each group's lanes hold identical wp/wn)
    wp += __shfl_xor(wp, 16); wp += __shfl_xor(wp, 32);
    wn += __shfl_xor(wn, 16); wn += __shfl_xor(wn, 32);

    __shared__ float sp[WAVES_PER_BLOCK], sn[WAVES_PER_BLOCK];
    if (lane == 0) { sp[wid] = wp; sn[wid] = wn; }
    __syncthreads();
    if (tid == 0) {
        float tp = sp[0] + sp[1] + sp[2] + sp[3];
        float tn = sn[0] + sn[1] + sn[2] + sn[3];
        ((float2*)ws)[sub * B + b] = make_float2(tp, tn);  // no atomics
    }
}

// ---------------- kernel 2: reduce block partials, per-batch loss, average ----------------
__global__ __launch_bounds__(256) void final_kernel(const float* __restrict__ ws,
                                                    float* __restrict__ out) {
    const float2* pp = (const float2*)ws;
    int tid = threadIdx.x;
    int lane = tid & 63, w = tid >> 6;
    int b = w * 8 + (lane >> 3);   // 0..31
    int h = lane & 7;              // 8 lanes per batch
    float ep = 0.0f, en = 0.0f;
    #pragma unroll
    for (int m = 0; m < 4; ++m) {  // subs h+8m cover 0..31
        float2 v = pp[(h + 8 * m) * B + b];
        ep += v.x; en += v.y;
    }
    #pragma unroll
    for (int off = 1; off <= 4; off <<= 1) {
        ep += __shfl_xor(ep, off);
        en += __shfl_xor(en, off);
    }
    __shared__ float2 acc[B];
    if (h == 0) acc[b] = make_float2(ep, en);
    __syncthreads();
    if (tid < B) {
        float2 a = acc[tid];
        float li = 0.0f; int v = 0;
        if (a.x > 0.0f && a.y > 0.0f) {  // == any(pos) && any(neg), since exp>0
            v = 1;
            li = -logf(a.x / (a.x + a.y + EPSF));
        }
        #pragma unroll
        for (int off = 16; off > 0; off >>= 1) {
            li += __shfl_xor(li, off);
            v  += __shfl_xor(v, off);
        }
        if (tid == 0) out[0] = li / (float)(v > 0 ? v : 1);
    }
}

extern "C" void kernel_launch(void* const* d_in, const int* in_sizes, int n_in,
                              void* d_out, int out_size, void* d_ws, size_t ws_size,
                              hipStream_t stream) {
    const float* pos_query = (const float*)d_in[0];  // (B,H) fp32
    const float* tmap      = (const float*)d_in[1];  // (B,S,S,H) fp32
    const int*   mask_pos  = (const int*)d_in[2];    // (B,S,S) bool -> int32
    const int*   mask_neg  = (const int*)d_in[3];
    float* out = (float*)d_out;
    float* ws  = (float*)d_ws;

    main_kernel<<<GRID, 256, 0, stream>>>(tmap, pos_query, mask_pos, mask_neg, ws);
    final_kernel<<<1, 256, 0, stream>>>(ws, out);
}